// Round 1
// baseline (2491.403 us; speedup 1.0000x reference)
//
#include <hip/hip_runtime.h>
#include <hip/hip_cooperative_groups.h>

namespace cg = cooperative_groups;

#define D 2048
#define T 1024
#define GI_STRIDE (3 * D)  // gi row: [r | z | n]

__device__ __forceinline__ float sigf(float x) {
    return 1.0f / (1.0f + __expf(-x));
}
__device__ __forceinline__ float tanhfast(float x) {
    float e = __expf(-2.0f * fabsf(x));
    float t = (1.0f - e) / (1.0f + e);
    return copysignf(t, x);
}

// ---------------------------------------------------------------------------
// Kernel A: input projections  gi[t][g][j] = X[t,:] @ W_g + b_g   (g = r,z,n)
// M=1024, N=6144 (3 gates x 2048), K=2048. Tile: 128(t) x 64(j), one gate/block.
// ---------------------------------------------------------------------------
__global__ __launch_bounds__(256) void kA(
    const float* __restrict__ X,
    const float* __restrict__ wir, const float* __restrict__ wiz, const float* __restrict__ win,
    const float* __restrict__ bir, const float* __restrict__ biz, const float* __restrict__ bin,
    float* __restrict__ gi)
{
    __shared__ float Xs[128 * 33];   // [m][k], stride 33 (pad breaks bank conflicts)
    __shared__ float Ws[32 * 64];    // [k][j]

    const int tid = threadIdx.x;
    const int tx = tid & 15;         // j group (4 cols)
    const int ty = tid >> 4;         // m group (8 rows)
    const int g  = blockIdx.x >> 5;
    const int jt = blockIdx.x & 31;
    const int j0 = jt * 64;
    const int t0 = blockIdx.y * 128;

    const float* __restrict__ W    = (g == 0) ? wir : (g == 1) ? wiz : win;
    const float* __restrict__ bias = (g == 0) ? bir : (g == 1) ? biz : bin;

    float acc[8][4];
#pragma unroll
    for (int i = 0; i < 8; ++i)
#pragma unroll
        for (int c = 0; c < 4; ++c) acc[i][c] = 0.0f;

    for (int k0 = 0; k0 < D; k0 += 32) {
        __syncthreads();
        // stage X tile: 128 x 32
#pragma unroll
        for (int it = 0; it < 4; ++it) {
            int l4 = tid + it * 256;
            int m = l4 >> 3, k4 = l4 & 7;
            float4 v = *(const float4*)&X[(t0 + m) * D + k0 + (k4 << 2)];
            float* dst = &Xs[m * 33 + (k4 << 2)];
            dst[0] = v.x; dst[1] = v.y; dst[2] = v.z; dst[3] = v.w;
        }
        // stage W tile: 32 x 64
#pragma unroll
        for (int it = 0; it < 2; ++it) {
            int l4 = tid + it * 256;
            int k = l4 >> 4, j4 = l4 & 15;
            *(float4*)&Ws[k * 64 + (j4 << 2)] =
                *(const float4*)&W[(k0 + k) * D + j0 + (j4 << 2)];
        }
        __syncthreads();
#pragma unroll
        for (int kk = 0; kk < 32; ++kk) {
            float4 wv = *(float4*)&Ws[kk * 64 + (tx << 2)];
#pragma unroll
            for (int i = 0; i < 8; ++i) {
                float x = Xs[(ty * 8 + i) * 33 + kk];
                acc[i][0] += x * wv.x;
                acc[i][1] += x * wv.y;
                acc[i][2] += x * wv.z;
                acc[i][3] += x * wv.w;
            }
        }
    }

    float4 bv = *(const float4*)&bias[j0 + (tx << 2)];
#pragma unroll
    for (int i = 0; i < 8; ++i) {
        int t = t0 + ty * 8 + i;
        float4 o;
        o.x = acc[i][0] + bv.x;
        o.y = acc[i][1] + bv.y;
        o.z = acc[i][2] + bv.z;
        o.w = acc[i][3] + bv.w;
        *(float4*)&gi[t * GI_STRIDE + g * D + j0 + (tx << 2)] = o;
    }
}

// ---------------------------------------------------------------------------
// Kernel B: segment extraction + counting sort by length (descending).
// Single block; flags loaded in parallel, rest serial on thread 0 (tiny).
// Outputs: st_sorted[p] = start time of sorted segment p,
//          n_active[s] = #segments with len > s, nseg, maxlen.
// ---------------------------------------------------------------------------
__global__ void kB(const int* __restrict__ term,
                   int* __restrict__ st_sorted, int* __restrict__ n_active,
                   int* __restrict__ nseg_out, int* __restrict__ maxlen_out)
{
    __shared__ int flags[T];
    __shared__ int starts[T + 1];
    __shared__ int lens[T];
    __shared__ int hist[T + 1];
    __shared__ int gt[T + 2];
    const int tid = threadIdx.x;
    for (int t = tid; t < T; t += 256) flags[t] = (t == 0) || (term[t] != 0);
    for (int i = tid; i <= T; i += 256) hist[i] = 0;
    __syncthreads();
    if (tid == 0) {
        int n = 0;
        for (int t = 0; t < T; ++t) if (flags[t]) starts[n++] = t;
        starts[n] = T;
        int maxlen = 0;
        for (int k = 0; k < n; ++k) {
            int L = starts[k + 1] - starts[k];
            lens[k] = L;
            hist[L]++;
            if (L > maxlen) maxlen = L;
        }
        int run = 0;
        for (int L = T; L >= 0; --L) { gt[L] = run; run += hist[L]; }
        for (int s = 0; s < maxlen; ++s) n_active[s] = gt[s];
        for (int k = 0; k < n; ++k) {
            int L = lens[k];
            st_sorted[gt[L]++] = starts[k];   // gt[L] doubles as cursor
        }
        nseg_out[0] = n;
        maxlen_out[0] = maxlen;
    }
}

// ---------------------------------------------------------------------------
// Kernel B2: initialize H row p (sorted order). t=0 segment with term[0]==0
// starts from last_state; everything else from zeros.
// ---------------------------------------------------------------------------
__global__ void kB2(const float* __restrict__ last_state, const int* __restrict__ term,
                    const int* __restrict__ st_sorted, const int* __restrict__ nseg_p,
                    float* __restrict__ Hb0)
{
    int p = blockIdx.x;
    if (p >= nseg_p[0]) return;
    bool useLast = (st_sorted[p] == 0) && (term[0] == 0);
    for (int j = threadIdx.x; j < D; j += 256)
        Hb0[p * D + j] = useLast ? last_state[j] : 0.0f;
}

// ---------------------------------------------------------------------------
// Kernel C (cooperative): macro-step loop. Each macro-step s:
//   for all sorted segments p < n_active[s]:  t = st[p] + s
//     [ar|az|an] = H[p,:] @ [Whr|Whz|Whn]   (GEMM, tiles 64(p) x 64(j) x 3 gates)
//     gate math -> h_new -> H_next[p,:], out[t,:], out[T+t,:]
// Double-buffered H; grid.sync() between macro-steps.
// ---------------------------------------------------------------------------
__global__ __launch_bounds__(256, 1) void kC(
    const float* __restrict__ whr, const float* __restrict__ whz, const float* __restrict__ whn,
    const float* __restrict__ bhn, const float* __restrict__ gi,
    float* __restrict__ Hb0, float* __restrict__ Hb1,
    const int* __restrict__ st, const int* __restrict__ n_active,
    const int* __restrict__ maxlen_p, float* __restrict__ out)
{
    cg::grid_group grid = cg::this_grid();
    __shared__ float Hs[64 * 33];
    __shared__ float Wrs[32 * 64];
    __shared__ float Wzs[32 * 64];
    __shared__ float Wns[32 * 64];

    const int tid = threadIdx.x;
    const int tx = tid & 15;   // j group (4 cols)
    const int ty = tid >> 4;   // m group (4 rows)
    const int maxlen = maxlen_p[0];

    for (int s = 0; s < maxlen; ++s) {
        const float* __restrict__ Hc = (s & 1) ? Hb1 : Hb0;
        float* __restrict__ Hn = (s & 1) ? Hb0 : Hb1;
        const int active = n_active[s];
        const int mtiles = (active + 63) >> 6;
        const int tiles = mtiles << 5;   // x 32 j-tiles

        for (int tile = blockIdx.x; tile < tiles; tile += gridDim.x) {
            const int p0 = (tile >> 5) << 6;
            const int j0 = (tile & 31) << 6;

            float ar[4][4], az[4][4], an[4][4];
#pragma unroll
            for (int i = 0; i < 4; ++i)
#pragma unroll
                for (int c = 0; c < 4; ++c) { ar[i][c] = 0.f; az[i][c] = 0.f; an[i][c] = 0.f; }

            for (int k0 = 0; k0 < D; k0 += 32) {
                __syncthreads();
                // stage H tile: 64 x 32
#pragma unroll
                for (int it = 0; it < 2; ++it) {
                    int l4 = tid + it * 256;
                    int m = l4 >> 3, k4 = l4 & 7;
                    float4 v = *(const float4*)&Hc[(p0 + m) * D + k0 + (k4 << 2)];
                    float* dst = &Hs[m * 33 + (k4 << 2)];
                    dst[0] = v.x; dst[1] = v.y; dst[2] = v.z; dst[3] = v.w;
                }
                // stage 3 W tiles: 32 x 64 each
#pragma unroll
                for (int it = 0; it < 2; ++it) {
                    int l4 = tid + it * 256;
                    int k = l4 >> 4, j4 = l4 & 15;
                    int ga = (k0 + k) * D + j0 + (j4 << 2);
                    int la = k * 64 + (j4 << 2);
                    *(float4*)&Wrs[la] = *(const float4*)&whr[ga];
                    *(float4*)&Wzs[la] = *(const float4*)&whz[ga];
                    *(float4*)&Wns[la] = *(const float4*)&whn[ga];
                }
                __syncthreads();
#pragma unroll
                for (int kk = 0; kk < 32; ++kk) {
                    float4 wr = *(float4*)&Wrs[kk * 64 + (tx << 2)];
                    float4 wz = *(float4*)&Wzs[kk * 64 + (tx << 2)];
                    float4 wn = *(float4*)&Wns[kk * 64 + (tx << 2)];
#pragma unroll
                    for (int i = 0; i < 4; ++i) {
                        float h = Hs[(ty * 4 + i) * 33 + kk];
                        ar[i][0] += h * wr.x; ar[i][1] += h * wr.y;
                        ar[i][2] += h * wr.z; ar[i][3] += h * wr.w;
                        az[i][0] += h * wz.x; az[i][1] += h * wz.y;
                        az[i][2] += h * wz.z; az[i][3] += h * wz.w;
                        an[i][0] += h * wn.x; an[i][1] += h * wn.y;
                        an[i][2] += h * wn.z; an[i][3] += h * wn.w;
                    }
                }
            }
            // epilogue: gate math + state/output writes
#pragma unroll
            for (int i = 0; i < 4; ++i) {
                int p = p0 + ty * 4 + i;
                if (p < active) {
                    int t = st[p] + s;
                    int j = j0 + (tx << 2);
                    const float4 gr = *(const float4*)&gi[t * GI_STRIDE + j];
                    const float4 gz = *(const float4*)&gi[t * GI_STRIDE + D + j];
                    const float4 gn = *(const float4*)&gi[t * GI_STRIDE + 2 * D + j];
                    const float4 bh = *(const float4*)&bhn[j];
                    const float4 ho = *(const float4*)&Hc[p * D + j];
                    float4 h4;
                    {
                        float r = sigf(ar[i][0] + gr.x);
                        float z = sigf(az[i][0] + gz.x);
                        float nn = tanhfast(gn.x + r * (an[i][0] + bh.x));
                        h4.x = (1.0f - z) * nn + z * ho.x;
                    }
                    {
                        float r = sigf(ar[i][1] + gr.y);
                        float z = sigf(az[i][1] + gz.y);
                        float nn = tanhfast(gn.y + r * (an[i][1] + bh.y));
                        h4.y = (1.0f - z) * nn + z * ho.y;
                    }
                    {
                        float r = sigf(ar[i][2] + gr.z);
                        float z = sigf(az[i][2] + gz.z);
                        float nn = tanhfast(gn.z + r * (an[i][2] + bh.z));
                        h4.z = (1.0f - z) * nn + z * ho.z;
                    }
                    {
                        float r = sigf(ar[i][3] + gr.w);
                        float z = sigf(az[i][3] + gz.w);
                        float nn = tanhfast(gn.w + r * (an[i][3] + bh.w));
                        h4.w = (1.0f - z) * nn + z * ho.w;
                    }
                    *(float4*)&Hn[p * D + j] = h4;
                    *(float4*)&out[t * D + j] = h4;            // y_t
                    *(float4*)&out[(T + t) * D + j] = h4;      // new_states
                }
            }
        }
        __threadfence();
        grid.sync();
    }
}

// ---------------------------------------------------------------------------
extern "C" void kernel_launch(void* const* d_in, const int* in_sizes, int n_in,
                              void* d_out, int out_size, void* d_ws, size_t ws_size,
                              hipStream_t stream)
{
    const float* X    = (const float*)d_in[0];
    const int*   term = (const int*)  d_in[1];
    const float* last = (const float*)d_in[2];
    const float* wir  = (const float*)d_in[3];
    const float* wiz  = (const float*)d_in[4];
    const float* win  = (const float*)d_in[5];
    const float* bir  = (const float*)d_in[6];
    const float* biz  = (const float*)d_in[7];
    const float* bin  = (const float*)d_in[8];
    const float* whr  = (const float*)d_in[9];
    const float* whz  = (const float*)d_in[10];
    const float* whn  = (const float*)d_in[11];
    const float* bhn  = (const float*)d_in[12];
    float* out = (float*)d_out;

    char* ws = (char*)d_ws;
    float* gi  = (float*)ws;                                   // T*3D f32 = 24 MB
    float* hb0 = (float*)(ws + (size_t)T * GI_STRIDE * 4);     // 1024*2048 f32 = 8 MB
    float* hb1 = (float*)(ws + (size_t)T * GI_STRIDE * 4 + (size_t)T * D * 4);
    int* meta = (int*)(ws + (size_t)T * GI_STRIDE * 4 + 2 * (size_t)T * D * 4);
    int* st       = meta;            // 1024
    int* n_active = meta + 1024;     // 1025
    int* nseg_p   = meta + 2049;
    int* maxlen_p = meta + 2050;

    kA<<<dim3(96, 8), 256, 0, stream>>>(X, wir, wiz, win, bir, biz, bin, gi);
    kB<<<1, 256, 0, stream>>>(term, st, n_active, nseg_p, maxlen_p);
    kB2<<<1024, 256, 0, stream>>>(last, term, st, nseg_p, hb0);

    const float* c_whr = whr; const float* c_whz = whz; const float* c_whn = whn;
    const float* c_bhn = bhn; const float* c_gi = gi;
    float* c_h0 = hb0; float* c_h1 = hb1;
    const int* c_st = st; const int* c_na = n_active; const int* c_ml = maxlen_p;
    float* c_out = out;
    void* args[] = {&c_whr, &c_whz, &c_whn, &c_bhn, &c_gi, &c_h0, &c_h1,
                    &c_st, &c_na, &c_ml, &c_out};
    hipLaunchCooperativeKernel((void*)kC, dim3(256), dim3(256), args, 0, stream);
}

// Round 2
// 2370.820 us; speedup vs baseline: 1.0509x; 1.0509x over previous
//
#include <hip/hip_runtime.h>
#include <hip/hip_cooperative_groups.h>

namespace cg = cooperative_groups;

#define D 2048
#define T 1024
#define GI_STRIDE (3 * D)  // gi row: [r | z | n]

__device__ __forceinline__ float sigf(float x) {
    return 1.0f / (1.0f + __expf(-x));
}
__device__ __forceinline__ float tanhfast(float x) {
    float e = __expf(-2.0f * fabsf(x));
    float t = (1.0f - e) / (1.0f + e);
    return copysignf(t, x);
}

// ---------------------------------------------------------------------------
// Kernel A: input projections  gi[t][g][j] = X[t,:] @ W_g + b_g   (g = r,z,n)
// M=1024, N=6144 (3 gates x 2048), K=2048. Tile: 128(t) x 64(j), one gate/block.
// ---------------------------------------------------------------------------
__global__ __launch_bounds__(256) void kA(
    const float* __restrict__ X,
    const float* __restrict__ wir, const float* __restrict__ wiz, const float* __restrict__ win,
    const float* __restrict__ bir, const float* __restrict__ biz, const float* __restrict__ bin,
    float* __restrict__ gi)
{
    __shared__ float Xs[128 * 33];
    __shared__ float Ws[32 * 64];

    const int tid = threadIdx.x;
    const int tx = tid & 15;
    const int ty = tid >> 4;
    const int g  = blockIdx.x >> 5;
    const int jt = blockIdx.x & 31;
    const int j0 = jt * 64;
    const int t0 = blockIdx.y * 128;

    const float* __restrict__ W    = (g == 0) ? wir : (g == 1) ? wiz : win;
    const float* __restrict__ bias = (g == 0) ? bir : (g == 1) ? biz : bin;

    float acc[8][4];
#pragma unroll
    for (int i = 0; i < 8; ++i)
#pragma unroll
        for (int c = 0; c < 4; ++c) acc[i][c] = 0.0f;

    for (int k0 = 0; k0 < D; k0 += 32) {
        __syncthreads();
#pragma unroll
        for (int it = 0; it < 4; ++it) {
            int l4 = tid + it * 256;
            int m = l4 >> 3, k4 = l4 & 7;
            float4 v = *(const float4*)&X[(t0 + m) * D + k0 + (k4 << 2)];
            float* dst = &Xs[m * 33 + (k4 << 2)];
            dst[0] = v.x; dst[1] = v.y; dst[2] = v.z; dst[3] = v.w;
        }
#pragma unroll
        for (int it = 0; it < 2; ++it) {
            int l4 = tid + it * 256;
            int k = l4 >> 4, j4 = l4 & 15;
            *(float4*)&Ws[k * 64 + (j4 << 2)] =
                *(const float4*)&W[(k0 + k) * D + j0 + (j4 << 2)];
        }
        __syncthreads();
#pragma unroll
        for (int kk = 0; kk < 32; ++kk) {
            float4 wv = *(float4*)&Ws[kk * 64 + (tx << 2)];
#pragma unroll
            for (int i = 0; i < 8; ++i) {
                float x = Xs[(ty * 8 + i) * 33 + kk];
                acc[i][0] += x * wv.x;
                acc[i][1] += x * wv.y;
                acc[i][2] += x * wv.z;
                acc[i][3] += x * wv.w;
            }
        }
    }

    float4 bv = *(const float4*)&bias[j0 + (tx << 2)];
#pragma unroll
    for (int i = 0; i < 8; ++i) {
        int t = t0 + ty * 8 + i;
        float4 o;
        o.x = acc[i][0] + bv.x;
        o.y = acc[i][1] + bv.y;
        o.z = acc[i][2] + bv.z;
        o.w = acc[i][3] + bv.w;
        *(float4*)&gi[t * GI_STRIDE + g * D + j0 + (tx << 2)] = o;
    }
}

// ---------------------------------------------------------------------------
// Kernel B: parallel segment extraction + counting sort by length (desc).
// Ballot-based: flags -> 16x 64-bit masks in LDS; per-start next-bit search;
// histogram via LDS atomics; tiny serial prefix over maxlen (<~20) bins.
// ---------------------------------------------------------------------------
__global__ void kB(const int* __restrict__ term,
                   int* __restrict__ st_sorted, int* __restrict__ n_active,
                   int* __restrict__ nseg_out, int* __restrict__ maxlen_out)
{
    __shared__ unsigned long long masks[16];
    __shared__ int hist[1025];
    __shared__ int off[1025];
    __shared__ int cur[1025];
    __shared__ int sh_maxlen;
    const int tid = threadIdx.x;
    if (tid == 0) sh_maxlen = 0;
    for (int i = tid; i < 1025; i += 256) { hist[i] = 0; cur[i] = 0; }
    __syncthreads();

    const int wid = tid >> 6;
#pragma unroll
    for (int it = 0; it < 4; ++it) {
        int t = it * 256 + tid;
        bool f = (t == 0) || (term[t] != 0);
        unsigned long long m = __ballot(f);
        if ((tid & 63) == 0) masks[it * 4 + wid] = m;
    }
    __syncthreads();

    int myt[4], mylen[4], cnt = 0;
#pragma unroll
    for (int it = 0; it < 4; ++it) {
        int t = it * 256 + tid;
        int w0 = t >> 6, b = t & 63;
        if ((masks[w0] >> b) & 1ULL) {
            int next = T;
            unsigned long long m = masks[w0] & ~((2ULL << b) - 1ULL);
            if (m) next = (w0 << 6) + __builtin_ctzll(m);
            else {
                for (int w = w0 + 1; w < 16; ++w)
                    if (masks[w]) { next = (w << 6) + __builtin_ctzll(masks[w]); break; }
            }
            int L = next - t;
            myt[cnt] = t; mylen[cnt] = L; ++cnt;
            atomicAdd(&hist[L], 1);
            atomicMax(&sh_maxlen, L);
        }
    }
    __syncthreads();
    if (tid == 0) {
        int run = 0, ml = sh_maxlen;
        for (int L = ml; L >= 1; --L) {
            off[L] = run;
            run += hist[L];
            n_active[L - 1] = run;   // #segments with len >= L  == active at step L-1
        }
        nseg_out[0] = run;
        maxlen_out[0] = ml;
    }
    __syncthreads();
    for (int c = 0; c < cnt; ++c) {
        int L = mylen[c];
        int pos = off[L] + atomicAdd(&cur[L], 1);
        st_sorted[pos] = myt[c];
    }
}

// ---------------------------------------------------------------------------
// Kernel B2: initialize H row p (sorted order).
// ---------------------------------------------------------------------------
__global__ void kB2(const float* __restrict__ last_state, const int* __restrict__ term,
                    const int* __restrict__ st_sorted, const int* __restrict__ nseg_p,
                    float* __restrict__ Hb0)
{
    int p = blockIdx.x;
    if (p >= nseg_p[0]) return;
    bool useLast = (st_sorted[p] == 0) && (term[0] == 0);
    for (int j = threadIdx.x; j < D; j += 256)
        Hb0[p * D + j] = useLast ? last_state[j] : 0.0f;
}

// ---------------------------------------------------------------------------
// Kernel C (cooperative): macro-step loop with adaptive split-K.
// Per step: mtiles = ceil(active/32); ksplit chosen so mtiles*32*ksplit ~= grid
// (capped: ksplit*rows_pad <= 512 rows of partial buffer, Kchunk >= 128).
//   ksplit==1: GEMM tile + fused gate epilogue (like round 1, 32-row tiles).
//   ksplit>1 : phase 1 writes fp32 partials -> grid.sync -> phase 2 reduces
//              ksplit partials + gate math + H/out writes.
// ---------------------------------------------------------------------------
__global__ __launch_bounds__(256, 2) void kC(
    const float* __restrict__ whr, const float* __restrict__ whz, const float* __restrict__ whn,
    const float* __restrict__ bhn, const float* __restrict__ gi,
    float* __restrict__ Hb0, float* __restrict__ Hb1,
    const int* __restrict__ st, const int* __restrict__ n_active,
    const int* __restrict__ maxlen_p, float* __restrict__ part,
    float* __restrict__ out)
{
    cg::grid_group grid = cg::this_grid();
    __shared__ float Hs[32 * 33];
    __shared__ float Wrs[32 * 64];
    __shared__ float Wzs[32 * 64];
    __shared__ float Wns[32 * 64];

    const int tid = threadIdx.x;
    const int tx = tid & 15;   // j group (4 cols)
    const int ty = tid >> 4;   // m group (2 rows)
    const int maxlen = maxlen_p[0];
    const int G = gridDim.x;

    for (int s = 0; s < maxlen; ++s) {
        const float* __restrict__ Hc = (s & 1) ? Hb1 : Hb0;
        float* __restrict__ Hn = (s & 1) ? Hb0 : Hb1;
        const int active = n_active[s];
        const int mtiles = (active + 31) >> 5;
        const int rows_pad = mtiles << 5;

        int ks = 1;
        while (ks < 16 && rows_pad * 32 * ks < G && rows_pad * ks * 2 <= 512) ks <<= 1;
        const int Klen = D / ks;
        const int tiles = mtiles * 32 * ks;

        for (int tile = blockIdx.x; tile < tiles; tile += G) {
            const int kidx = tile / (mtiles * 32);
            const int rem  = tile - kidx * (mtiles * 32);
            const int p0 = (rem >> 5) << 5;
            const int j0 = (rem & 31) << 6;
            const int kbeg = kidx * Klen;

            float ar[2][4], az[2][4], an[2][4];
#pragma unroll
            for (int i = 0; i < 2; ++i)
#pragma unroll
                for (int c = 0; c < 4; ++c) { ar[i][c] = 0.f; az[i][c] = 0.f; an[i][c] = 0.f; }

            for (int k0 = kbeg; k0 < kbeg + Klen; k0 += 32) {
                __syncthreads();
                {   // stage H tile: 32 x 32, one float4/thread
                    int m = tid >> 3, k4 = (tid & 7) << 2;
                    float4 v = *(const float4*)&Hc[(size_t)(p0 + m) * D + k0 + k4];
                    float* dst = &Hs[m * 33 + k4];
                    dst[0] = v.x; dst[1] = v.y; dst[2] = v.z; dst[3] = v.w;
                }
#pragma unroll
                for (int it = 0; it < 2; ++it) {   // stage 3 W tiles: 32 x 64
                    int l4 = tid + it * 256;
                    int k = l4 >> 4, j4 = (l4 & 15) << 2;
                    size_t ga = (size_t)(k0 + k) * D + j0 + j4;
                    int la = k * 64 + j4;
                    *(float4*)&Wrs[la] = *(const float4*)&whr[ga];
                    *(float4*)&Wzs[la] = *(const float4*)&whz[ga];
                    *(float4*)&Wns[la] = *(const float4*)&whn[ga];
                }
                __syncthreads();
#pragma unroll
                for (int kk = 0; kk < 32; ++kk) {
                    float4 wr = *(float4*)&Wrs[kk * 64 + (tx << 2)];
                    float4 wz = *(float4*)&Wzs[kk * 64 + (tx << 2)];
                    float4 wn = *(float4*)&Wns[kk * 64 + (tx << 2)];
#pragma unroll
                    for (int i = 0; i < 2; ++i) {
                        float h = Hs[(ty * 2 + i) * 33 + kk];
                        ar[i][0] += h * wr.x; ar[i][1] += h * wr.y;
                        ar[i][2] += h * wr.z; ar[i][3] += h * wr.w;
                        az[i][0] += h * wz.x; az[i][1] += h * wz.y;
                        az[i][2] += h * wz.z; az[i][3] += h * wz.w;
                        an[i][0] += h * wn.x; an[i][1] += h * wn.y;
                        an[i][2] += h * wn.z; an[i][3] += h * wn.w;
                    }
                }
            }

            if (ks == 1) {
#pragma unroll
                for (int i = 0; i < 2; ++i) {
                    int p = p0 + ty * 2 + i;
                    if (p < active) {
                        int t = st[p] + s;
                        int j = j0 + (tx << 2);
                        const float4 gr = *(const float4*)&gi[(size_t)t * GI_STRIDE + j];
                        const float4 gz = *(const float4*)&gi[(size_t)t * GI_STRIDE + D + j];
                        const float4 gn = *(const float4*)&gi[(size_t)t * GI_STRIDE + 2 * D + j];
                        const float4 bh = *(const float4*)&bhn[j];
                        const float4 ho = *(const float4*)&Hc[(size_t)p * D + j];
                        float4 h4;
                        {
                            float r = sigf(ar[i][0] + gr.x);
                            float z = sigf(az[i][0] + gz.x);
                            float nn = tanhfast(gn.x + r * (an[i][0] + bh.x));
                            h4.x = (1.0f - z) * nn + z * ho.x;
                        }
                        {
                            float r = sigf(ar[i][1] + gr.y);
                            float z = sigf(az[i][1] + gz.y);
                            float nn = tanhfast(gn.y + r * (an[i][1] + bh.y));
                            h4.y = (1.0f - z) * nn + z * ho.y;
                        }
                        {
                            float r = sigf(ar[i][2] + gr.z);
                            float z = sigf(az[i][2] + gz.z);
                            float nn = tanhfast(gn.z + r * (an[i][2] + bh.z));
                            h4.z = (1.0f - z) * nn + z * ho.z;
                        }
                        {
                            float r = sigf(ar[i][3] + gr.w);
                            float z = sigf(az[i][3] + gz.w);
                            float nn = tanhfast(gn.w + r * (an[i][3] + bh.w));
                            h4.w = (1.0f - z) * nn + z * ho.w;
                        }
                        *(float4*)&Hn[(size_t)p * D + j] = h4;
                        *(float4*)&out[(size_t)t * D + j] = h4;
                        *(float4*)&out[(size_t)(T + t) * D + j] = h4;
                    }
                }
            } else {
#pragma unroll
                for (int i = 0; i < 2; ++i) {
                    int p = p0 + ty * 2 + i;
                    int j = j0 + (tx << 2);
                    size_t base = (size_t)(kidx * rows_pad + p) * 3 * D + j;
                    float4 v;
                    v.x = ar[i][0]; v.y = ar[i][1]; v.z = ar[i][2]; v.w = ar[i][3];
                    *(float4*)&part[base] = v;
                    v.x = az[i][0]; v.y = az[i][1]; v.z = az[i][2]; v.w = az[i][3];
                    *(float4*)&part[base + D] = v;
                    v.x = an[i][0]; v.y = an[i][1]; v.z = an[i][2]; v.w = an[i][3];
                    *(float4*)&part[base + 2 * D] = v;
                }
            }
        }

        if (ks > 1) {
            __threadfence();
            grid.sync();
            // phase 2: reduce partials + gate math. One float4 column group/iter.
            const int gtid = blockIdx.x * 256 + tid;
            const int total = active << 9;  // active rows * 512 float4-groups
            for (int idx = gtid; idx < total; idx += G * 256) {
                const int p = idx >> 9;
                const int j = (idx & 511) << 2;
                const int t = st[p] + s;
                float srx = 0, sry = 0, srz = 0, srw = 0;
                float szx = 0, szy = 0, szz = 0, szw = 0;
                float snx = 0, sny = 0, snz = 0, snw = 0;
                for (int kq = 0; kq < ks; ++kq) {
                    size_t base = (size_t)(kq * rows_pad + p) * 3 * D + j;
                    float4 a = *(const float4*)&part[base];
                    float4 b = *(const float4*)&part[base + D];
                    float4 c = *(const float4*)&part[base + 2 * D];
                    srx += a.x; sry += a.y; srz += a.z; srw += a.w;
                    szx += b.x; szy += b.y; szz += b.z; szw += b.w;
                    snx += c.x; sny += c.y; snz += c.z; snw += c.w;
                }
                const float4 gr = *(const float4*)&gi[(size_t)t * GI_STRIDE + j];
                const float4 gz = *(const float4*)&gi[(size_t)t * GI_STRIDE + D + j];
                const float4 gn = *(const float4*)&gi[(size_t)t * GI_STRIDE + 2 * D + j];
                const float4 bh = *(const float4*)&bhn[j];
                const float4 ho = *(const float4*)&Hc[(size_t)p * D + j];
                float4 h4;
                {
                    float r = sigf(srx + gr.x);
                    float z = sigf(szx + gz.x);
                    float nn = tanhfast(gn.x + r * (snx + bh.x));
                    h4.x = (1.0f - z) * nn + z * ho.x;
                }
                {
                    float r = sigf(sry + gr.y);
                    float z = sigf(szy + gz.y);
                    float nn = tanhfast(gn.y + r * (sny + bh.y));
                    h4.y = (1.0f - z) * nn + z * ho.y;
                }
                {
                    float r = sigf(srz + gr.z);
                    float z = sigf(szz + gz.z);
                    float nn = tanhfast(gn.z + r * (snz + bh.z));
                    h4.z = (1.0f - z) * nn + z * ho.z;
                }
                {
                    float r = sigf(srw + gr.w);
                    float z = sigf(szw + gz.w);
                    float nn = tanhfast(gn.w + r * (snw + bh.w));
                    h4.w = (1.0f - z) * nn + z * ho.w;
                }
                *(float4*)&Hn[(size_t)p * D + j] = h4;
                *(float4*)&out[(size_t)t * D + j] = h4;
                *(float4*)&out[(size_t)(T + t) * D + j] = h4;
            }
        }
        __threadfence();
        grid.sync();
    }
}

// ---------------------------------------------------------------------------
extern "C" void kernel_launch(void* const* d_in, const int* in_sizes, int n_in,
                              void* d_out, int out_size, void* d_ws, size_t ws_size,
                              hipStream_t stream)
{
    const float* X    = (const float*)d_in[0];
    const int*   term = (const int*)  d_in[1];
    const float* last = (const float*)d_in[2];
    const float* wir  = (const float*)d_in[3];
    const float* wiz  = (const float*)d_in[4];
    const float* win  = (const float*)d_in[5];
    const float* bir  = (const float*)d_in[6];
    const float* biz  = (const float*)d_in[7];
    const float* bin  = (const float*)d_in[8];
    const float* whr  = (const float*)d_in[9];
    const float* whz  = (const float*)d_in[10];
    const float* whn  = (const float*)d_in[11];
    const float* bhn  = (const float*)d_in[12];
    float* out = (float*)d_out;

    char* ws = (char*)d_ws;
    size_t off = 0;
    float* gi  = (float*)(ws + off); off += (size_t)T * GI_STRIDE * 4;   // 24 MB
    float* hb0 = (float*)(ws + off); off += (size_t)T * D * 4;           // 8 MB
    float* hb1 = (float*)(ws + off); off += (size_t)T * D * 4;           // 8 MB
    float* part = (float*)(ws + off); off += (size_t)512 * 3 * D * 4;    // 12.6 MB
    int* meta = (int*)(ws + off);
    int* st       = meta;            // 1024
    int* n_active = meta + 1024;     // 1024
    int* nseg_p   = meta + 2048;
    int* maxlen_p = meta + 2049;

    kA<<<dim3(96, 8), 256, 0, stream>>>(X, wir, wiz, win, bir, biz, bin, gi);
    kB<<<1, 256, 0, stream>>>(term, st, n_active, nseg_p, maxlen_p);
    kB2<<<1024, 256, 0, stream>>>(last, term, st, nseg_p, hb0);

    int maxB = 0;
    if (hipOccupancyMaxActiveBlocksPerMultiprocessor(&maxB, kC, 256, 0) != hipSuccess || maxB < 1)
        maxB = 1;
    int grid = maxB * 256;
    if (grid > 512) grid = 512;

    const float* c_whr = whr; const float* c_whz = whz; const float* c_whn = whn;
    const float* c_bhn = bhn; const float* c_gi = gi;
    float* c_h0 = hb0; float* c_h1 = hb1;
    const int* c_st = st; const int* c_na = n_active; const int* c_ml = maxlen_p;
    float* c_part = part; float* c_out = out;
    void* args[] = {&c_whr, &c_whz, &c_whn, &c_bhn, &c_gi, &c_h0, &c_h1,
                    &c_st, &c_na, &c_ml, &c_part, &c_out};
    hipLaunchCooperativeKernel((void*)kC, dim3(grid), dim3(256), args, 0, stream);
}